// Round 5
// baseline (760.273 us; speedup 1.0000x reference)
//
#include <hip/hip_runtime.h>

// Problem constants (fixed by the reference's setup_inputs)
#define QS_ 512
#define B_  8
#define C_  1024
#define H_  16
#define HC_ 64
#define M_  1536
#define KS_ 512
#define NSPLIT 4
#define TSPLIT 512

typedef __attribute__((ext_vector_type(8))) short bf16x8;
typedef __attribute__((ext_vector_type(4))) float f32x4;

__device__ __forceinline__ short f2bf(float f) {
    unsigned u = __float_as_uint(f);
    unsigned r = (u + 0x7FFF + ((u >> 16) & 1)) >> 16;   // RNE
    return (short)r;
}
__device__ __forceinline__ float bf2f(short s) {
    return __uint_as_float(((unsigned)(unsigned short)s) << 16);
}

__device__ __forceinline__ void gload_lds16(const void* g, void* l) {
    __builtin_amdgcn_global_load_lds(
        (const __attribute__((address_space(1))) unsigned int*)g,
        (__attribute__((address_space(3))) unsigned int*)l, 16, 0, 0);
}

// ---------------------------------------------------------------------------
// f32 -> bf16 elementwise convert. 8 elems/thread.
// ---------------------------------------------------------------------------
__global__ __launch_bounds__(256) void cvt_f32_bf16(
    const float* __restrict__ src, short* __restrict__ dst, int n8)
{
    int i = blockIdx.x * 256 + threadIdx.x;
    if (i >= n8) return;
    const float4* s = (const float4*)src + (size_t)i * 2;
    float4 a = s[0], bq = s[1];
    short o[8];
    o[0] = f2bf(a.x);  o[1] = f2bf(a.y);  o[2] = f2bf(a.z);  o[3] = f2bf(a.w);
    o[4] = f2bf(bq.x); o[5] = f2bf(bq.y); o[6] = f2bf(bq.z); o[7] = f2bf(bq.w);
    *(uint4*)(dst + (size_t)i * 8) = *(uint4*)o;
}

// ---------------------------------------------------------------------------
// memory_kv [t][b][h][128] f32  ->  bf16 [b][h][t][128].
// ---------------------------------------------------------------------------
__global__ __launch_bounds__(256) void mkv_reshape_bf16(
    const float* __restrict__ mkv, short* __restrict__ dst)
{
    int gid = blockIdx.x * 256 + threadIdx.x;   // 0 .. M*B*H*4-1
    int part = gid & 3;
    int row  = gid >> 2;                        // t*B*H + b*H + h
    int h = row & (H_ - 1);
    int tb = row >> 4;
    int b = tb & (B_ - 1);
    int t = tb >> 3;
    const float4* s = (const float4*)(mkv + (size_t)row * 128 + part * 32);
    short o[32];
#pragma unroll
    for (int j = 0; j < 8; ++j) {
        float4 f = s[j];
        o[j * 4 + 0] = f2bf(f.x); o[j * 4 + 1] = f2bf(f.y);
        o[j * 4 + 2] = f2bf(f.z); o[j * 4 + 3] = f2bf(f.w);
    }
    short* d = dst + (((size_t)(b * H_ + h) * M_ + t) * 128 + part * 32);
#pragma unroll
    for (int j = 0; j < 4; ++j)
        ((uint4*)d)[j] = ((uint4*)o)[j];
}

// ---------------------------------------------------------------------------
// m97-style bf16 NT GEMM (unchanged from R4): 128(M)x64(N) tile, BK=64,
// global_load_lds width-16 staging, grid (32,16)=512 blocks.
// ---------------------------------------------------------------------------
template <bool BF16OUT>
__global__ __launch_bounds__(256) void gemm_bt_bf16(
    const short* __restrict__ A, const short* __restrict__ W,
    const float* __restrict__ bias, void* __restrict__ outv)
{
    __shared__ short As[128][64];
    __shared__ short Ws[64][64];
    const int tid  = threadIdx.x;
    const int lane = tid & 63;
    const int wave = tid >> 6;
    const int wm = (wave & 1) * 64;
    const int wn = (wave >> 1) * 32;
    const int lr = lane & 15;
    const int quad = lane >> 4;
    const int n0 = blockIdx.x * 128;
    const int j0 = blockIdx.y * 64;

    f32x4 acc[4][2];
#pragma unroll
    for (int i = 0; i < 4; ++i)
#pragma unroll
        for (int j = 0; j < 2; ++j)
            acc[i][j] = (f32x4){0.f, 0.f, 0.f, 0.f};

    for (int k0 = 0; k0 < C_; k0 += 64) {
#pragma unroll
        for (int p = 0; p < 4; ++p) {
            int flat = p * 256 + tid;
            int r = flat >> 3, c8 = (flat & 7) * 8;
            gload_lds16(A + (size_t)(n0 + r) * C_ + k0 + c8, (short*)As + flat * 8);
        }
#pragma unroll
        for (int p = 0; p < 2; ++p) {
            int flat = p * 256 + tid;
            int r = flat >> 3, c8 = (flat & 7) * 8;
            gload_lds16(W + (size_t)(j0 + r) * C_ + k0 + c8, (short*)Ws + flat * 8);
        }
        __syncthreads();
#pragma unroll
        for (int ks = 0; ks < 2; ++ks) {
            const int kk = ks * 32 + quad * 8;
            bf16x8 afrag[4], bfrag[2];
#pragma unroll
            for (int im = 0; im < 4; ++im)
                afrag[im] = *(const bf16x8*)&As[wm + im * 16 + lr][kk];
#pragma unroll
            for (int jn = 0; jn < 2; ++jn)
                bfrag[jn] = *(const bf16x8*)&Ws[wn + jn * 16 + lr][kk];
#pragma unroll
            for (int im = 0; im < 4; ++im)
#pragma unroll
                for (int jn = 0; jn < 2; ++jn)
                    acc[im][jn] = __builtin_amdgcn_mfma_f32_16x16x32_bf16(
                        afrag[im], bfrag[jn], acc[im][jn], 0, 0, 0);
        }
        __syncthreads();
    }

#pragma unroll
    for (int jn = 0; jn < 2; ++jn) {
        const int col = j0 + wn + jn * 16 + lr;
        const float bv = bias[col];
#pragma unroll
        for (int im = 0; im < 4; ++im) {
            const int row = n0 + wm + im * 16 + quad * 4;
#pragma unroll
            for (int r = 0; r < 4; ++r) {
                float v = acc[im][jn][r] + bv;
                if (BF16OUT)
                    ((short*)outv)[(size_t)(row + r) * C_ + col] = f2bf(v);
                else
                    ((float*)outv)[(size_t)(row + r) * C_ + col] = v;
            }
        }
    }
}

// ---------------------------------------------------------------------------
// Flash-decoding attention, t-split across blocks.
// Block = 64 q rows x (h,b) x split; grid 4096, (split,b) fastest.
// Emits unnormalized partial O (bf16) + (m,l) per q-row per split.
// ---------------------------------------------------------------------------
__global__ __launch_bounds__(256) void mem_attn_split(
    const short* __restrict__ qb, const short* __restrict__ kb,
    const short* __restrict__ vb, const short* __restrict__ mkvb,
    const int* __restrict__ mlen, const int* __restrict__ padv,
    const unsigned char* __restrict__ maskb,
    short* __restrict__ Opart, float2* __restrict__ ml)
{
    __shared__ short Ks[64][72];   // [t_local][hc]
    __shared__ short Vt[64][72];   // [hc][t_local]
    __shared__ short Pl[64][72];   // [q_local][t_local]
    const int tid  = threadIdx.x;
    const int lane = tid & 63;
    const int wave = tid >> 6;
    const int lr   = lane & 15;
    const int quad = lane >> 4;
    const int bx = blockIdx.x;
    const int split = bx & 3;
    const int b  = (bx >> 2) & 7;
    const int h  = (bx >> 5) & 15;
    const int s0 = (bx >> 9) * 64;
    const int L  = mlen[b];
    const int P  = padv[b];
    const int tend = L + P;
    const float NEG = -1e30f;

    const size_t ebase = ((((size_t)split * B_ + b) * H_ + h) * QS_);  // + s

    const int tbeg   = split * TSPLIT;
    const int tend_s = (tend < tbeg + TSPLIT) ? tend : (tbeg + TSPLIT);
    if (tbeg >= tend_s) {
        // empty split: record l=0 so combine skips it
        if (tid < 64) ml[ebase + s0 + tid] = make_float2(NEG, 0.f);
        return;
    }

    // Q fragments straight from global (once)
    const short* qrow = qb + ((size_t)(s0 + wave * 16 + lr) * B_ + b) * C_ + h * HC_;
    bf16x8 aq0 = *(const bf16x8*)(qrow + quad * 8);
    bf16x8 aq1 = *(const bf16x8*)(qrow + 32 + quad * 8);

    f32x4 Oacc[4];
#pragma unroll
    for (int i = 0; i < 4; ++i) Oacc[i] = (f32x4){0.f, 0.f, 0.f, 0.f};
    float mrow[4] = {NEG, NEG, NEG, NEG};
    float lrow[4] = {0.f, 0.f, 0.f, 0.f};

    const int tl = tid >> 2;      // staging row 0..63
    const int cg = tid & 3;       // col group
    const int c0 = cg * 16;
    const short* mkvbase = mkvb + (size_t)(b * H_ + h) * M_ * 128;

    const int nch = (tend_s - tbeg + 63) >> 6;
    for (int ci = 0; ci < nch; ++ci) {
        const int t0 = tbeg + (ci << 6);
        const int t  = t0 + tl;
        // ---- stage K row and V^T column group ----
        short tk[16], tv[16];
        if (t < L) {
            const short* src = mkvbase + (size_t)t * 128;
            *(uint4*)&tk[0] = *(const uint4*)(src + c0);
            *(uint4*)&tk[8] = *(const uint4*)(src + c0 + 8);
            *(uint4*)&tv[0] = *(const uint4*)(src + 64 + c0);
            *(uint4*)&tv[8] = *(const uint4*)(src + 64 + c0 + 8);
        } else if (t - L < P) {
            const short* ksrc = kb + ((size_t)(t - L) * B_ + b) * C_ + h * HC_ + c0;
            const short* vsrc = vb + ((size_t)(t - L) * B_ + b) * C_ + h * HC_ + c0;
            *(uint4*)&tk[0] = *(const uint4*)ksrc;
            *(uint4*)&tk[8] = *(const uint4*)(ksrc + 8);
            *(uint4*)&tv[0] = *(const uint4*)vsrc;
            *(uint4*)&tv[8] = *(const uint4*)(vsrc + 8);
        } else {
#pragma unroll
            for (int j = 0; j < 16; ++j) { tk[j] = 0; tv[j] = 0; }
        }
        *(uint4*)&Ks[tl][c0]     = *(uint4*)&tk[0];
        *(uint4*)&Ks[tl][c0 + 8] = *(uint4*)&tk[8];
#pragma unroll
        for (int jj = 0; jj < 16; ++jj) {
            int j = (jj + cg) & 15;
            Vt[c0 + j][tl] = tv[j];
        }
        __syncthreads();

        // ---- S = Q . K^T ----
        f32x4 S[4];
#pragma unroll
        for (int tt = 0; tt < 4; ++tt) {
            bf16x8 bk0 = *(const bf16x8*)&Ks[tt * 16 + lr][quad * 8];
            bf16x8 bk1 = *(const bf16x8*)&Ks[tt * 16 + lr][32 + quad * 8];
            f32x4 z = (f32x4){0.f, 0.f, 0.f, 0.f};
            z = __builtin_amdgcn_mfma_f32_16x16x32_bf16(aq0, bk0, z, 0, 0, 0);
            S[tt] = __builtin_amdgcn_mfma_f32_16x16x32_bf16(aq1, bk1, z, 0, 0, 0);
        }

        // ---- mask + online softmax (C layout: row=quad*4+r, col=lr) ----
        float Sv[4][4];
        float rowmax[4] = {NEG, NEG, NEG, NEG};
#pragma unroll
        for (int tt = 0; tt < 4; ++tt) {
            const int tcol = t0 + tt * 16 + lr;
            const bool in_mem = tcol < L;
            const int off = tcol - L;
            const bool in_new = !in_mem && (off < P);
#pragma unroll
            for (int r = 0; r < 4; ++r) {
                float val = S[tt][r] * 0.125f;
                bool masked;
                if (in_mem) masked = false;
                else if (in_new) {
                    const int s = s0 + wave * 16 + quad * 4 + r;
                    masked = maskb[((size_t)s * KS_ + off) * B_ + b] != 0;
                } else masked = true;
                val = masked ? NEG : val;
                Sv[tt][r] = val;
                rowmax[r] = fmaxf(rowmax[r], val);
            }
        }
#pragma unroll
        for (int r = 0; r < 4; ++r) {
            float rm = rowmax[r];
            rm = fmaxf(rm, __shfl_xor(rm, 1, 16));
            rm = fmaxf(rm, __shfl_xor(rm, 2, 16));
            rm = fmaxf(rm, __shfl_xor(rm, 4, 16));
            rm = fmaxf(rm, __shfl_xor(rm, 8, 16));
            rowmax[r] = rm;
        }
        float pv[4][4];
#pragma unroll
        for (int r = 0; r < 4; ++r) {
            float nm = fmaxf(mrow[r], rowmax[r]);
            float al = __expf(mrow[r] - nm);
            float rs = 0.f;
#pragma unroll
            for (int tt = 0; tt < 4; ++tt) {
                float p = (Sv[tt][r] == NEG) ? 0.f : __expf(Sv[tt][r] - nm);
                pv[tt][r] = p;
                rs += p;
            }
            rs += __shfl_xor(rs, 1, 16);
            rs += __shfl_xor(rs, 2, 16);
            rs += __shfl_xor(rs, 4, 16);
            rs += __shfl_xor(rs, 8, 16);
            lrow[r] = lrow[r] * al + rs;
            mrow[r] = nm;
#pragma unroll
            for (int ht = 0; ht < 4; ++ht) Oacc[ht][r] *= al;
        }
        // ---- P (bf16) -> LDS A-layout, quad-rotated ----
#pragma unroll
        for (int jj = 0; jj < 4; ++jj) {
            int tt = (jj + quad) & 3;
#pragma unroll
            for (int r = 0; r < 4; ++r)
                Pl[wave * 16 + quad * 4 + r][tt * 16 + lr] = f2bf(pv[tt][r]);
        }
        __syncthreads();

        // ---- O += P . V ----
        bf16x8 ap0 = *(const bf16x8*)&Pl[wave * 16 + lr][quad * 8];
        bf16x8 ap1 = *(const bf16x8*)&Pl[wave * 16 + lr][32 + quad * 8];
#pragma unroll
        for (int ht = 0; ht < 4; ++ht) {
            bf16x8 bv0 = *(const bf16x8*)&Vt[ht * 16 + lr][quad * 8];
            bf16x8 bv1 = *(const bf16x8*)&Vt[ht * 16 + lr][32 + quad * 8];
            Oacc[ht] = __builtin_amdgcn_mfma_f32_16x16x32_bf16(ap0, bv0, Oacc[ht], 0, 0, 0);
            Oacc[ht] = __builtin_amdgcn_mfma_f32_16x16x32_bf16(ap1, bv1, Oacc[ht], 0, 0, 0);
        }
        __syncthreads();
    }

    // ---- epilogue: write unnormalized partials ----
#pragma unroll
    for (int r = 0; r < 4; ++r) {
        const int s = s0 + wave * 16 + quad * 4 + r;
        if (lr == 0) ml[ebase + s] = make_float2(mrow[r], lrow[r]);
        short* orow = Opart + (ebase + s) * 64;
#pragma unroll
        for (int ht = 0; ht < 4; ++ht)
            orow[ht * 16 + lr] = f2bf(Oacc[ht][r]);
    }
}

// ---------------------------------------------------------------------------
// Combine NSPLIT partials per q-row: x = sum_i exp(m_i-M) O_i / sum_i l_i exp(m_i-M)
// One thread = 16 dims of one (s,b,h) row.
// ---------------------------------------------------------------------------
__global__ __launch_bounds__(256) void attn_combine(
    const short* __restrict__ Opart, const float2* __restrict__ ml,
    short* __restrict__ xbuf)
{
    int gid = blockIdx.x * 256 + threadIdx.x;     // 0..262143
    int part = gid & 3;
    int r = gid >> 2;            // 0..65535
    int s = r & 511;
    int h = (r >> 9) & 15;
    int b = r >> 13;
    const float NEG = -1e30f;
    float m_[NSPLIT], l_[NSPLIT];
    float M = NEG;
#pragma unroll
    for (int sp = 0; sp < NSPLIT; ++sp) {
        float2 t = ml[(((size_t)sp * B_ + b) * H_ + h) * QS_ + s];
        m_[sp] = t.x; l_[sp] = t.y;
        if (l_[sp] > 0.f) M = fmaxf(M, m_[sp]);
    }
    float acc[16] = {};
    float denom = 0.f;
#pragma unroll
    for (int sp = 0; sp < NSPLIT; ++sp) {
        if (l_[sp] > 0.f) {
            float w = __expf(m_[sp] - M);
            denom += l_[sp] * w;
            const short* op = Opart + ((((size_t)sp * B_ + b) * H_ + h) * QS_ + s) * 64 + part * 16;
            uint4 u0 = ((const uint4*)op)[0];
            uint4 u1 = ((const uint4*)op)[1];
            const short* o0 = (const short*)&u0;
            const short* o1 = (const short*)&u1;
#pragma unroll
            for (int d = 0; d < 8; ++d) acc[d]     += w * bf2f(o0[d]);
#pragma unroll
            for (int d = 0; d < 8; ++d) acc[8 + d] += w * bf2f(o1[d]);
        }
    }
    float inv = denom > 0.f ? 1.0f / denom : 0.f;
    short o[16];
#pragma unroll
    for (int d = 0; d < 16; ++d) o[d] = f2bf(acc[d] * inv);
    short* dst = xbuf + ((size_t)s * B_ + b) * C_ + h * HC_ + part * 16;
    ((uint4*)dst)[0] = *(uint4*)&o[0];
    ((uint4*)dst)[1] = *(uint4*)&o[8];
}

// ---------------------------------------------------------------------------
extern "C" void kernel_launch(void* const* d_in, const int* in_sizes, int n_in,
                              void* d_out, int out_size, void* d_ws, size_t ws_size,
                              hipStream_t stream)
{
    const float* xq   = (const float*)d_in[0];
    const int*   pad  = (const int*)d_in[1];
    const unsigned char* maskb = (const unsigned char*)d_in[2];
    const int*   mlen = (const int*)d_in[3];
    const float* mkv  = (const float*)d_in[4];
    const float* Wq   = (const float*)d_in[5];
    const float* bq   = (const float*)d_in[6];
    const float* Wk   = (const float*)d_in[7];
    const float* bk   = (const float*)d_in[8];
    const float* Wv   = (const float*)d_in[9];
    const float* bv   = (const float*)d_in[10];
    const float* Wo   = (const float*)d_in[11];
    const float* bo   = (const float*)d_in[12];
    float* out = (float*)d_out;

    // Workspace layout (shorts), total ~137 MiB
    short* xqb   = (short*)d_ws;
    short* wqb   = xqb   + (size_t)4194304;
    short* wkb   = wqb   + (size_t)1048576;
    short* wvb   = wkb   + (size_t)1048576;
    short* wob   = wvb   + (size_t)1048576;
    short* mkvb  = wob   + (size_t)1048576;     // 25,165,824 elems
    short* qbuf  = mkvb  + (size_t)25165824;
    short* kbuf  = qbuf  + (size_t)4194304;
    short* vbuf  = kbuf  + (size_t)4194304;
    short* xbuf  = vbuf  + (size_t)4194304;
    short* opart = xbuf  + (size_t)4194304;     // 4*8*16*512*64 = 16,777,216
    float2* mlb  = (float2*)(opart + (size_t)16777216);  // 262,144 float2

    dim3 gblk(256);
    // 1) bf16 pre-conversions
    cvt_f32_bf16<<<dim3(2048), gblk, 0, stream>>>(xq, xqb, 524288);
    cvt_f32_bf16<<<dim3(512),  gblk, 0, stream>>>(Wq, wqb, 131072);
    cvt_f32_bf16<<<dim3(512),  gblk, 0, stream>>>(Wk, wkb, 131072);
    cvt_f32_bf16<<<dim3(512),  gblk, 0, stream>>>(Wv, wvb, 131072);
    cvt_f32_bf16<<<dim3(512),  gblk, 0, stream>>>(Wo, wob, 131072);
    mkv_reshape_bf16<<<dim3(3072), gblk, 0, stream>>>(mkv, mkvb);

    // 2) q/k/v projections (bf16 out)
    dim3 ggemm(32, 16);   // 4096/128 x 1024/64
    gemm_bt_bf16<true><<<ggemm, gblk, 0, stream>>>(xqb, wqb, bq, qbuf);
    gemm_bt_bf16<true><<<ggemm, gblk, 0, stream>>>(xqb, wkb, bk, kbuf);
    gemm_bt_bf16<true><<<ggemm, gblk, 0, stream>>>(xqb, wvb, bv, vbuf);

    // 3) attention, t-split 4x; (split,b) fastest in flat grid
    mem_attn_split<<<dim3(4096), gblk, 0, stream>>>(qbuf, kbuf, vbuf, mkvb,
                                                    mlen, pad, maskb, opart, mlb);
    attn_combine<<<dim3(1024), gblk, 0, stream>>>(opart, mlb, xbuf);

    // 4) output projection (f32 out)
    gemm_bt_bf16<false><<<ggemm, gblk, 0, stream>>>(xbuf, wob, bo, out);
}

// Round 6
// 559.166 us; speedup vs baseline: 1.3597x; 1.3597x over previous
//
#include <hip/hip_runtime.h>

// Problem constants (fixed by the reference's setup_inputs)
#define QS_ 512
#define B_  8
#define C_  1024
#define H_  16
#define HC_ 64
#define M_  1536
#define KS_ 512
#define TDIM 2048
#define VND 640    // padded new-V row: (L&7)+pad(512)+64+7 <= 583 < 640

typedef __attribute__((ext_vector_type(8))) short bf16x8;
typedef __attribute__((ext_vector_type(4))) float f32x4;

__device__ __forceinline__ short f2bf(float f) {
    unsigned u = __float_as_uint(f);
    unsigned r = (u + 0x7FFF + ((u >> 16) & 1)) >> 16;   // RNE
    return (short)r;
}

__device__ __forceinline__ void gload_lds16(const void* g, void* l) {
    __builtin_amdgcn_global_load_lds(
        (const __attribute__((address_space(1))) unsigned int*)g,
        (__attribute__((address_space(3))) unsigned int*)l, 16, 0, 0);
}

// ---------------------------------------------------------------------------
// f32 -> bf16 elementwise convert. 8 elems/thread.
// ---------------------------------------------------------------------------
__global__ __launch_bounds__(256) void cvt_f32_bf16(
    const float* __restrict__ src, short* __restrict__ dst, int n8)
{
    int i = blockIdx.x * 256 + threadIdx.x;
    if (i >= n8) return;
    const float4* s = (const float4*)src + (size_t)i * 2;
    float4 a = s[0], bq = s[1];
    short o[8];
    o[0] = f2bf(a.x);  o[1] = f2bf(a.y);  o[2] = f2bf(a.z);  o[3] = f2bf(a.w);
    o[4] = f2bf(bq.x); o[5] = f2bf(bq.y); o[6] = f2bf(bq.z); o[7] = f2bf(bq.w);
    *(uint4*)(dst + (size_t)i * 8) = *(uint4*)o;
}

// ---------------------------------------------------------------------------
// memory_kv [t][b][h][128] f32 -> K bf16 [b*H+h][t][64]  (direct)
//                              -> V bf16 [b*H+h][hc][1536] (LDS transpose)
// Block = (t-chunk 64, h, b).
// ---------------------------------------------------------------------------
__global__ __launch_bounds__(256) void mkv_prep(
    const float* __restrict__ mkv, short* __restrict__ kOut,
    short* __restrict__ vOut)
{
    __shared__ short T[64][72];
    const int tc = blockIdx.x, h = blockIdx.y, b = blockIdx.z;
    const int tid = threadIdx.x;
    const int row = tid >> 2, part = tid & 3;
    const int t = tc * 64 + row;
    const int g = b * H_ + h;
    const float4* src = (const float4*)(mkv + (((size_t)t * B_ + b) * H_ + h) * 128 + part * 32);
    short o[32];
#pragma unroll
    for (int j = 0; j < 8; ++j) {
        float4 f = src[j];
        o[j * 4 + 0] = f2bf(f.x); o[j * 4 + 1] = f2bf(f.y);
        o[j * 4 + 2] = f2bf(f.z); o[j * 4 + 3] = f2bf(f.w);
    }
    if (part < 2) {   // K half: cols 0..63
        short* d = kOut + ((size_t)g * M_ + t) * 64 + part * 32;
#pragma unroll
        for (int j = 0; j < 4; ++j) ((uint4*)d)[j] = ((uint4*)o)[j];
    } else {          // V half: cols 64..127 -> transpose via LDS
        int hc0 = (part - 2) * 32;
#pragma unroll
        for (int j = 0; j < 32; ++j) T[hc0 + j][row] = o[j];
    }
    __syncthreads();
    const int hc = tid >> 2, seg = tid & 3;
    uint4 a = *(const uint4*)&T[hc][seg * 16];
    uint4 c = *(const uint4*)&T[hc][seg * 16 + 8];
    short* d = vOut + ((size_t)g * HC_ + hc) * M_ + tc * 64 + seg * 16;
    ((uint4*)d)[0] = a; ((uint4*)d)[1] = c;
}

// ---------------------------------------------------------------------------
// vbuf [s][b][C] bf16 -> vnewT [b*H+h][hc][VND] at column (L&7)+s
// (absolute-t-aligned so attention V-fragment loads stay 16B aligned).
// Block = (s-chunk 64, h, b).
// ---------------------------------------------------------------------------
__global__ __launch_bounds__(256) void v_transpose(
    const short* __restrict__ vbuf, const int* __restrict__ mlen,
    short* __restrict__ vOut)
{
    __shared__ short T[64][72];
    const int sc = blockIdx.x, h = blockIdx.y, b = blockIdx.z;
    const int tid = threadIdx.x;
    const int r = tid >> 2, seg = tid & 3;
    const int s = sc * 64 + r;
    const short* src = vbuf + ((size_t)s * B_ + b) * C_ + h * HC_ + seg * 16;
    short tmp[16];
    *(uint4*)&tmp[0] = ((const uint4*)src)[0];
    *(uint4*)&tmp[8] = ((const uint4*)src)[1];
#pragma unroll
    for (int j = 0; j < 16; ++j) T[seg * 16 + j][r] = tmp[j];
    __syncthreads();
    const int L7 = mlen[b] & 7;
    const int hc = tid >> 2;
    const int g = b * H_ + h;
    short* drow = vOut + ((size_t)g * HC_ + hc) * VND + L7 + sc * 64 + seg * 16;
    const short* srow = &T[hc][seg * 16];
#pragma unroll
    for (int j = 0; j < 16; ++j) drow[j] = srow[j];   // scalar: dst may be odd-aligned
}

// ---------------------------------------------------------------------------
// m97-style bf16 NT GEMM: 128x128 tile, BK=64, global_load_lds width-16,
// 4 waves each 64x64 quadrant (4x4 16x16x32 tiles). Grid (32,8).
// ---------------------------------------------------------------------------
template <bool BF16OUT>
__global__ __launch_bounds__(256) void gemm128(
    const short* __restrict__ A, const short* __restrict__ W,
    const float* __restrict__ bias, void* __restrict__ outv)
{
    __shared__ short As[128][64];
    __shared__ short Ws[128][64];
    const int tid  = threadIdx.x;
    const int lane = tid & 63;
    const int wave = tid >> 6;
    const int wm = (wave & 1) * 64;
    const int wn = (wave >> 1) * 64;
    const int lr = lane & 15;
    const int quad = lane >> 4;
    const int n0 = blockIdx.x * 128;
    const int j0 = blockIdx.y * 128;

    f32x4 acc[4][4];
#pragma unroll
    for (int i = 0; i < 4; ++i)
#pragma unroll
        for (int j = 0; j < 4; ++j)
            acc[i][j] = (f32x4){0.f, 0.f, 0.f, 0.f};

    for (int k0 = 0; k0 < C_; k0 += 64) {
#pragma unroll
        for (int p = 0; p < 4; ++p) {
            int flat = p * 256 + tid;
            int r = flat >> 3, c8 = (flat & 7) * 8;
            gload_lds16(A + (size_t)(n0 + r) * C_ + k0 + c8, (short*)As + flat * 8);
        }
#pragma unroll
        for (int p = 0; p < 4; ++p) {
            int flat = p * 256 + tid;
            int r = flat >> 3, c8 = (flat & 7) * 8;
            gload_lds16(W + (size_t)(j0 + r) * C_ + k0 + c8, (short*)Ws + flat * 8);
        }
        __syncthreads();
#pragma unroll
        for (int ks = 0; ks < 2; ++ks) {
            const int kk = ks * 32 + quad * 8;
            bf16x8 afrag[4], bfrag[4];
#pragma unroll
            for (int im = 0; im < 4; ++im)
                afrag[im] = *(const bf16x8*)&As[wm + im * 16 + lr][kk];
#pragma unroll
            for (int jn = 0; jn < 4; ++jn)
                bfrag[jn] = *(const bf16x8*)&Ws[wn + jn * 16 + lr][kk];
#pragma unroll
            for (int im = 0; im < 4; ++im)
#pragma unroll
                for (int jn = 0; jn < 4; ++jn)
                    acc[im][jn] = __builtin_amdgcn_mfma_f32_16x16x32_bf16(
                        afrag[im], bfrag[jn], acc[im][jn], 0, 0, 0);
        }
        __syncthreads();
    }

#pragma unroll
    for (int jn = 0; jn < 4; ++jn) {
        const int col = j0 + wn + jn * 16 + lr;
        const float bv = bias[col];
#pragma unroll
        for (int im = 0; im < 4; ++im) {
            const int row = n0 + wm + im * 16 + quad * 4;
#pragma unroll
            for (int r = 0; r < 4; ++r) {
                float v = acc[im][jn][r] + bv;
                if (BF16OUT)
                    ((short*)outv)[(size_t)(row + r) * C_ + col] = f2bf(v);
                else
                    ((float*)outv)[(size_t)(row + r) * C_ + col] = v;
            }
        }
    }
}

// ---------------------------------------------------------------------------
// Barrier-free, LDS-free flash attention. One wave = 16 q-rows x (h,b) x all t.
// S^T = K.Q^T (A=K rows, B=Q rows); O^T = V^T.P^T (A=V t-major, B=P^T via
// 32 in-wave shuffles). All fragments loaded straight from global.
// Lane (quad,lr): softmax state for q = s0w+lr only; cross-quad reduce =
// shfl_xor 16,32. Grid 1024 blocks x 4 waves; bx%8 groups same (b,h) on one
// XCD for L2 sharing of the K/V stream.
// ---------------------------------------------------------------------------
__global__ __launch_bounds__(256) void attn_wave(
    const short* __restrict__ qb, const short* __restrict__ kbuf,
    const short* __restrict__ kmem, const short* __restrict__ vmem,
    const short* __restrict__ vnew, const int* __restrict__ mlen,
    const int* __restrict__ padv, const unsigned char* __restrict__ maskb,
    short* __restrict__ xout)
{
    const int tid  = threadIdx.x;
    const int lane = tid & 63;
    const int wave = tid >> 6;
    const int lr   = lane & 15;
    const int quad = lane >> 4;
    const int bx = blockIdx.x;
    const int g = bx & 127;            // b*16+h; bx%8 = g%8 -> XCD grouping
    const int b = g >> 4, h = g & 15;
    const int s0w = ((bx >> 7) * 4 + wave) * 16;
    const int L = mlen[b], P = padv[b];
    const int tend = L + P;
    const int Lbase = L & ~7;
    const float NEG = -1e30f;

    // Q fragments (persistent)
    const short* qrow = qb + ((size_t)(s0w + lr) * B_ + b) * C_ + h * HC_;
    bf16x8 q0 = *(const bf16x8*)(qrow + quad * 8);
    bf16x8 q1 = *(const bf16x8*)(qrow + 32 + quad * 8);

    const short* kmb = kmem + (size_t)g * M_ * 64 + quad * 8;
    const short* knb = kbuf + (size_t)b * C_ + h * HC_ + quad * 8;   // + s*(B_*C_)
    const short* vmb = vmem + (size_t)g * HC_ * M_;
    const short* vnb = vnew + (size_t)g * HC_ * VND;
    const int q = s0w + lr;

    f32x4 O[4];
#pragma unroll
    for (int i = 0; i < 4; ++i) O[i] = (f32x4){0.f, 0.f, 0.f, 0.f};
    float mr = NEG, lsum = 0.f;

    const int nch = (tend + 63) >> 6;
    for (int ci = 0; ci < nch; ++ci) {
        const int t0 = ci << 6;

        // ---- K fragments: A[m=t(lr)][k=hc(quad*8+j)] ----
        bf16x8 kf[4][2];
#pragma unroll
        for (int tt = 0; tt < 4; ++tt) {
            int t = t0 + tt * 16 + lr;
            const short* p = (t < L)
                ? (kmb + (size_t)t * 64)
                : (knb + (size_t)min(t - L, KS_ - 1) * (B_ * C_));
            kf[tt][0] = *(const bf16x8*)p;
            kf[tt][1] = *(const bf16x8*)(p + 32);
        }

        // ---- S^T = K . Q^T ----
        f32x4 S[4];
#pragma unroll
        for (int tt = 0; tt < 4; ++tt) {
            f32x4 z = (f32x4){0.f, 0.f, 0.f, 0.f};
            z = __builtin_amdgcn_mfma_f32_16x16x32_bf16(kf[tt][0], q0, z, 0, 0, 0);
            S[tt] = __builtin_amdgcn_mfma_f32_16x16x32_bf16(kf[tt][1], q1, z, 0, 0, 0);
        }

        // ---- V fragments (issued now; waited at PV): A[m=hc(lr)][k=t] ----
        bf16x8 vf[4][2];
        const bool slowV = (L > t0) && (L < t0 + 64) && ((L & 7) != 0);
        if (!slowV) {
#pragma unroll
            for (int hf = 0; hf < 2; ++hf) {
                int tf = t0 + hf * 32 + quad * 8;
                bool inmem = tf < L;
#pragma unroll
                for (int ht = 0; ht < 4; ++ht) {
                    int hc = ht * 16 + lr;
                    const short* p = inmem ? (vmb + (size_t)hc * M_ + tf)
                                           : (vnb + (size_t)hc * VND + (tf - Lbase));
                    vf[ht][hf] = *(const bf16x8*)p;
                }
            }
        } else {  // chunk straddles L at non-8-aligned boundary (rare, wave-uniform)
#pragma unroll
            for (int hf = 0; hf < 2; ++hf)
#pragma unroll
                for (int ht = 0; ht < 4; ++ht) {
                    short tmp[8];
                    int hc = ht * 16 + lr;
#pragma unroll
                    for (int j = 0; j < 8; ++j) {
                        int t = t0 + hf * 32 + quad * 8 + j;
                        tmp[j] = (t < L) ? vmb[(size_t)hc * M_ + t]
                                         : vnb[(size_t)hc * VND + (t - Lbase)];
                    }
                    vf[ht][hf] = *(const bf16x8*)tmp;
                }
        }

        // ---- mask + scale; lane value (tt,r) is (q=lr, t=t0+tt*16+quad*4+r) ----
        float p4[4][4];
        const bool anyNew = (t0 + 63 >= L);
#pragma unroll
        for (int tt = 0; tt < 4; ++tt)
#pragma unroll
            for (int r = 0; r < 4; ++r) {
                float val = S[tt][r] * 0.125f;
                if (anyNew) {
                    int t = t0 + tt * 16 + quad * 4 + r;
                    if (t >= L) {
                        int off = t - L;
                        bool masked = true;
                        if (off < P)
                            masked = (maskb[((size_t)q * KS_ + off) * B_ + b] != 0);
                        if (masked) val = NEG;
                    }
                }
                p4[tt][r] = val;
            }

        // ---- online softmax for q=lr (reduce across quads: xor 16,32) ----
        float rm = NEG;
#pragma unroll
        for (int tt = 0; tt < 4; ++tt)
#pragma unroll
            for (int r = 0; r < 4; ++r) rm = fmaxf(rm, p4[tt][r]);
        rm = fmaxf(rm, __shfl_xor(rm, 16, 64));
        rm = fmaxf(rm, __shfl_xor(rm, 32, 64));
        float nm = fmaxf(mr, rm);
        float al = __expf(mr - nm);
        float rs = 0.f;
#pragma unroll
        for (int tt = 0; tt < 4; ++tt)
#pragma unroll
            for (int r = 0; r < 4; ++r) {
                float e = (p4[tt][r] == NEG) ? 0.f : __expf(p4[tt][r] - nm);
                p4[tt][r] = e;
                rs += e;
            }
        rs += __shfl_xor(rs, 16, 64);
        rs += __shfl_xor(rs, 32, 64);
        lsum = lsum * al + rs;
        mr = nm;
#pragma unroll
        for (int ht = 0; ht < 4; ++ht)
#pragma unroll
            for (int r = 0; r < 4; ++r) O[ht][r] *= al;

        // ---- P^T fragments via in-wave shuffles:
        //      B[n=q(lr)][k=t(quad*8+j)] from C-layout S^T tiles ----
        bf16x8 pf[2];
#pragma unroll
        for (int hf = 0; hf < 2; ++hf) {
            const int tt0 = hf * 2;
            const int slA = ((quad & 1) * 2) * 16 + lr;
            const int slB = slA + 16;
            const bool hi = (quad & 2) != 0;
            short fr[8];
#pragma unroll
            for (int r = 0; r < 4; ++r) {
                float a0 = __shfl(p4[tt0][r],     slA, 64);
                float a1 = __shfl(p4[tt0 + 1][r], slA, 64);
                float b0 = __shfl(p4[tt0][r],     slB, 64);
                float b1 = __shfl(p4[tt0 + 1][r], slB, 64);
                fr[r]     = f2bf(hi ? a1 : a0);
                fr[4 + r] = f2bf(hi ? b1 : b0);
            }
            pf[hf] = *(const bf16x8*)fr;
        }

        // ---- O^T += V^T . P^T ----
#pragma unroll
        for (int ht = 0; ht < 4; ++ht) {
            O[ht] = __builtin_amdgcn_mfma_f32_16x16x32_bf16(vf[ht][0], pf[0], O[ht], 0, 0, 0);
            O[ht] = __builtin_amdgcn_mfma_f32_16x16x32_bf16(vf[ht][1], pf[1], O[ht], 0, 0, 0);
        }
    }

    // ---- epilogue: O^T C-layout row=hc=ht*16+quad*4+r, col=q=lr ----
    float inv = (lsum > 0.f) ? 1.0f / lsum : 0.f;
#pragma unroll
    for (int ht = 0; ht < 4; ++ht) {
        short ov[4];
#pragma unroll
        for (int r = 0; r < 4; ++r) ov[r] = f2bf(O[ht][r] * inv);
        short* d = xout + ((size_t)q * B_ + b) * C_ + h * HC_ + ht * 16 + quad * 4;
        *(long long*)d = *(const long long*)ov;
    }
}

// ---------------------------------------------------------------------------
extern "C" void kernel_launch(void* const* d_in, const int* in_sizes, int n_in,
                              void* d_out, int out_size, void* d_ws, size_t ws_size,
                              hipStream_t stream)
{
    const float* xq   = (const float*)d_in[0];
    const int*   pad  = (const int*)d_in[1];
    const unsigned char* maskb = (const unsigned char*)d_in[2];
    const int*   mlen = (const int*)d_in[3];
    const float* mkv  = (const float*)d_in[4];
    const float* Wq   = (const float*)d_in[5];
    const float* bq   = (const float*)d_in[6];
    const float* Wk   = (const float*)d_in[7];
    const float* bk   = (const float*)d_in[8];
    const float* Wv   = (const float*)d_in[9];
    const float* bv   = (const float*)d_in[10];
    const float* Wo   = (const float*)d_in[11];
    const float* bo   = (const float*)d_in[12];
    float* out = (float*)d_out;

    // Workspace layout (shorts), ~120 MiB
    short* xqb  = (short*)d_ws;
    short* wqb  = xqb  + (size_t)4194304;                 // 512*8*1024
    short* wkb  = wqb  + (size_t)1048576;
    short* wvb  = wkb  + (size_t)1048576;
    short* wob  = wvb  + (size_t)1048576;
    short* kmem = wob  + (size_t)1048576;                 // 128*1536*64 = 12.58M
    short* vmem = kmem + (size_t)128 * M_ * 64;           // 128*64*1536 = 12.58M
    short* vnew = vmem + (size_t)128 * HC_ * M_;          // 128*64*640  = 5.24M
    short* qbuf = vnew + (size_t)128 * HC_ * VND;
    short* kbuf = qbuf + (size_t)4194304;
    short* vbuf = kbuf + (size_t)4194304;
    short* xbuf = vbuf + (size_t)4194304;

    dim3 gblk(256);
    // 1) bf16 pre-conversions + memory_kv prep (K direct, V transposed)
    cvt_f32_bf16<<<dim3(2048), gblk, 0, stream>>>(xq, xqb, 524288);
    cvt_f32_bf16<<<dim3(512),  gblk, 0, stream>>>(Wq, wqb, 131072);
    cvt_f32_bf16<<<dim3(512),  gblk, 0, stream>>>(Wk, wkb, 131072);
    cvt_f32_bf16<<<dim3(512),  gblk, 0, stream>>>(Wv, wvb, 131072);
    cvt_f32_bf16<<<dim3(512),  gblk, 0, stream>>>(Wo, wob, 131072);
    mkv_prep<<<dim3(24, 16, 8), gblk, 0, stream>>>(mkv, kmem, vmem);

    // 2) q/k/v projections (bf16 out), m97 128x128 shape
    dim3 ggemm(32, 8);
    gemm128<true><<<ggemm, gblk, 0, stream>>>(xqb, wqb, bq, qbuf);
    gemm128<true><<<ggemm, gblk, 0, stream>>>(xqb, wkb, bk, kbuf);
    gemm128<true><<<ggemm, gblk, 0, stream>>>(xqb, wvb, bv, vbuf);
    v_transpose<<<dim3(8, 16, 8), gblk, 0, stream>>>(vbuf, mlen, vnew);

    // 3) barrier-free attention
    attn_wave<<<dim3(1024), gblk, 0, stream>>>(qbuf, kbuf, kmem, vmem, vnew,
                                               mlen, pad, maskb, xbuf);

    // 4) output projection (f32 out)
    gemm128<false><<<ggemm, gblk, 0, stream>>>(xbuf, wob, bo, out);
}